// Round 16
// baseline (331.037 us; speedup 1.0000x reference)
//
#include <hip/hip_runtime.h>
#include <hip/hip_fp16.h>

#define N_NODES 50000
#define N_EDGES 800000
#define ETOT    (N_EDGES + N_NODES)   // edges + self loops
#define NEG_SLOPE 0.2f
#define NBIN    ((N_NODES + 255) / 256)     // 196 coarse bins (dst>>8)
#define CHUNK   4096
#define B_COARSE ((ETOT + CHUNK - 1) / CHUNK)  // 208 blocks
#define G_NODE1 ((N_NODES + 3) / 4)            // 12500 blocks for node1 part

__device__ __forceinline__ float leaky(float v) {
    return v > 0.f ? v : NEG_SLOPE * v;
}

__device__ __forceinline__ void edge_src_dst(const int* ei, int e, int& src, int& dst) {
    if (e < N_EDGES) { src = ei[e]; dst = ei[N_EDGES + e]; }
    else             { src = dst = e - N_EDGES; }
}

// ======== Fused: layer-1 logits + packed {as1,x} record + coarse histogram ========
// xs1[node] = {as1_h0, as1_h1, x0..x5}: 32B aligned -> ONE 64B line per edge gather
__global__ void k_pre(const float* __restrict__ x, const float* __restrict__ W1,
                      const float* __restrict__ a_src1, const float* __restrict__ a_dst1,
                      float* __restrict__ xs1, float* __restrict__ ad1,
                      const int* __restrict__ ei, int* __restrict__ bh) {
    __shared__ int h[NBIN];
    if (blockIdx.x < G_NODE1) {
        int node = blockIdx.x * 4 + (threadIdx.x >> 6);
        if (node >= N_NODES) return;
        int j = threadIdx.x & 63;
        int head = j >> 5;
        float xk[6];
#pragma unroll
        for (int k = 0; k < 6; ++k)
            xk[k] = x[node * 6 + k];
        float hv = 0.f;
#pragma unroll
        for (int k = 0; k < 6; ++k)
            hv += xk[k] * W1[k * 64 + j];
        float s = hv * a_src1[j];
        float d = hv * a_dst1[j];
#pragma unroll
        for (int m = 1; m < 32; m <<= 1) {
            s += __shfl_xor(s, m);
            d += __shfl_xor(d, m);
        }
        if ((j & 31) == 0) {
            xs1[node * 8 + head] = s;          // slots 0,1: alpha_src per head
            ad1[node * 2 + head] = d;
        }
        if (j >= 2 && j < 8)
            xs1[node * 8 + j] = xk[j - 2];     // slots 2..7: x row
    } else {
        int b = blockIdx.x - G_NODE1;
        for (int i = threadIdx.x; i < NBIN; i += 256) h[i] = 0;
        __syncthreads();
        int base = b * CHUNK;
        int lim = min(base + CHUNK, ETOT);
        for (int e = base + threadIdx.x; e < lim; e += 256) {
            int s, d; edge_src_dst(ei, e, s, d);
            atomicAdd(&h[d >> 8], 1);
        }
        __syncthreads();
        for (int i = threadIdx.x; i < NBIN; i += 256)
            bh[b * NBIN + i] = h[i];
    }
}

// Parallel segmented scan: one block per bin scans its 208 per-chunk counts
__global__ void k_cscan_a(int* __restrict__ bh, int* __restrict__ bintot) {
    __shared__ int s[256];
    int bin = blockIdx.x;
    int t = threadIdx.x;
    int v = (t < B_COARSE) ? bh[t * NBIN + bin] : 0;
    int x = v;
    s[t] = x;
    __syncthreads();
#pragma unroll
    for (int o = 1; o < 256; o <<= 1) {
        int tt = (t >= o) ? s[t - o] : 0;
        __syncthreads();
        x += tt;
        s[t] = x;
        __syncthreads();
    }
    if (t < B_COARSE) bh[t * NBIN + bin] = x - v;
    if (t == 255) bintot[bin] = x;
}

// Tiny cross-bin exclusive scan of the 196 totals
__global__ void k_cscan_b(const int* __restrict__ bintot, int* __restrict__ binoff) {
    __shared__ int s[256];
    int t = threadIdx.x;
    int v = (t < NBIN) ? bintot[t] : 0;
    int x = v;
    s[t] = x;
    __syncthreads();
#pragma unroll
    for (int o = 1; o < 256; o <<= 1) {
        int tt = (t >= o) ? s[t - o] : 0;
        __syncthreads();
        x += tt;
        s[t] = x;
        __syncthreads();
    }
    if (t < NBIN) binoff[t] = x - v;
    if (t == 255) binoff[NBIN] = x;          // == ETOT
}

__global__ void k_cscatter(const int* __restrict__ ei, const int* __restrict__ bh,
                           const int* __restrict__ binoff, unsigned* __restrict__ ebin) {
    __shared__ int cur[NBIN];
    for (int i = threadIdx.x; i < NBIN; i += 256)
        cur[i] = bh[blockIdx.x * NBIN + i] + binoff[i];
    __syncthreads();
    int base = blockIdx.x * CHUNK;
    int lim = min(base + CHUNK, ETOT);
    for (int e = base + threadIdx.x; e < lim; e += 256) {
        int s, d; edge_src_dst(ei, e, s, d);
        int pos = atomicAdd(&cur[d >> 8], 1);
        ebin[pos] = ((unsigned)s << 8) | (unsigned)(d & 255);
    }
}

// ============ Layer 1 bin-local: unsorted edge accumulate (LDS atomics) ============
// + W1 epilogue + node2 transform, all per bin of 256 dst nodes. No fine sort needed.
__global__ __launch_bounds__(512) void k_gat1bin(
    const unsigned* __restrict__ ebin, const int* __restrict__ binoff,
    const float* __restrict__ xs1, const float* __restrict__ ad1,
    const float* __restrict__ W1, const float* __restrict__ b1,
    const float* __restrict__ W2, const float* __restrict__ as_w2,
    const float* __restrict__ ad_w2, __half* __restrict__ h2h,
    float* __restrict__ as2, float* __restrict__ ad2) {
    __shared__ float accD[256 * 15];   // per node: dp0,dp1, Σw0*x[6], Σw1*x[6] (stride 15: odd -> bank spread)
    __shared__ float o1s[32 * 66];     // 32-node o1 subtile, stride 66 bank-safe
    __shared__ float W2s[64 * 32];
    int t = threadIdx.x;
    int bin = blockIdx.x;
    for (int i = t; i < 256 * 15; i += 512) accD[i] = 0.f;
    for (int i = t; i < 64 * 32; i += 512) W2s[i] = W2[i];

    int l = t & 15;
    float p[4][6], bv[4];
#pragma unroll
    for (int m = 0; m < 4; ++m) {
        int c = l + 16 * m;
#pragma unroll
        for (int k = 0; k < 6; ++k)
            p[m][k] = W1[k * 64 + c];
        bv[m] = b1[c];
    }
    __syncthreads();

    // ---- phase A: edge accumulate (one 64B xs1 line per edge) ----
    int beg = binoff[bin], end = binoff[bin + 1];
    const float2* ad1f2 = (const float2*)ad1;
    for (int i = beg + t; i < end; i += 512) {
        unsigned e = ebin[i];
        int s = (int)(e >> 8);
        int d = (int)(e & 255u);
        float2 adv = ad1f2[bin * 256 + d];
        const float4* xp = (const float4*)(xs1 + (size_t)s * 8);
        float4 A = xp[0], B = xp[1];   // A = {as0, as1, x0, x1}, B = {x2..x5}
        float w0 = __expf(leaky(A.x + adv.x));   // logits O(1): no max needed
        float w1 = __expf(leaky(A.y + adv.y));
        float* r = accD + d * 15;
        atomicAdd(r + 0, w0);          atomicAdd(r + 1, w1);
        atomicAdd(r + 2, w0 * A.z);    atomicAdd(r + 3, w0 * A.w);
        atomicAdd(r + 4, w0 * B.x);    atomicAdd(r + 5, w0 * B.y);
        atomicAdd(r + 6, w0 * B.z);    atomicAdd(r + 7, w0 * B.w);
        atomicAdd(r + 8, w1 * A.z);    atomicAdd(r + 9, w1 * A.w);
        atomicAdd(r + 10, w1 * B.x);   atomicAdd(r + 11, w1 * B.y);
        atomicAdd(r + 12, w1 * B.z);   atomicAdd(r + 13, w1 * B.w);
    }
    __syncthreads();

    // ---- phase B: per-32-node subtiles: W1 epilogue -> o1s -> node2 ----
    int ln = t >> 4;                    // 0..31
    for (int sub = 0; sub < 8; ++sub) {
        int nl = sub * 32 + ln;
        int node = bin * 256 + nl;
        const float* r = accD + nl * 15;
        float inv0 = 1.f / r[0];
        float inv1 = 1.f / r[1];
#pragma unroll
        for (int m = 0; m < 4; ++m) {
            const float* xr = (m < 2) ? (r + 2) : (r + 8);
            float dot = xr[0] * p[m][0] + xr[1] * p[m][1] + xr[2] * p[m][2]
                      + xr[3] * p[m][3] + xr[4] * p[m][4] + xr[5] * p[m][5];
            float v = dot * (m < 2 ? inv0 : inv1) + bv[m];
            o1s[ln * 66 + l + 16 * m] = v > 0.f ? v : 0.f;   // bias+relu
        }
        __syncthreads();
        float h0 = 0.f, h1 = 0.f;
#pragma unroll
        for (int k = 0; k < 64; ++k) {
            float ov = o1s[ln * 66 + k];
            h0 += ov * W2s[k * 32 + l];
            h1 += ov * W2s[k * 32 + l + 16];
        }
        float s2 = h0 * as_w2[l] + h1 * as_w2[l + 16];
        float d2 = h0 * ad_w2[l] + h1 * ad_w2[l + 16];
#pragma unroll
        for (int o = 8; o; o >>= 1) {
            s2 += __shfl_xor(s2, o);
            d2 += __shfl_xor(d2, o);
        }
        if (node < N_NODES) {
            h2h[node * 32 + l] = __float2half(h0);
            h2h[node * 32 + l + 16] = __float2half(h1);
            if (l == 0) { as2[node] = s2; ad2[node] = d2; }
        }
        __syncthreads();
    }
}

// ============ Layer 2 bin-local: unsorted edge accumulate + output head ============
__global__ __launch_bounds__(512) void k_gat2bin(
    const unsigned* __restrict__ ebin, const int* __restrict__ binoff,
    const float* __restrict__ as2, const float* __restrict__ ad2,
    const __half2* __restrict__ h2h2, const float* __restrict__ b2,
    const float* __restrict__ Wout, const float* __restrict__ bout,
    float* __restrict__ out) {
    __shared__ float acc2[256 * 33];   // per node: 32 feature sums + dp (stride 33 bank-safe)
    __shared__ float b2s[32], wos[32];
    int t = threadIdx.x;
    int bin = blockIdx.x;
    for (int i = t; i < 256 * 33; i += 512) acc2[i] = 0.f;
    if (t < 32) { b2s[t] = b2[t]; wos[t] = Wout[t]; }
    __syncthreads();

    int beg = binoff[bin], end = binoff[bin + 1];
    int g = t >> 4;    // edge group 0..31
    int f = t & 15;    // feature pair
    for (int i = beg + g; i < end; i += 32) {
        unsigned e = ebin[i];                 // same addr across 16 lanes -> broadcast
        int s = (int)(e >> 8);
        int d = (int)(e & 255u);
        float w = __expf(leaky(as2[s] + ad2[bin * 256 + d]));
        float2 hv = __half22float2(h2h2[s * 16 + f]);
        float* r = acc2 + d * 33;
        atomicAdd(r + 2 * f, w * hv.x);
        atomicAdd(r + 2 * f + 1, w * hv.y);
        if (f == 0) atomicAdd(r + 32, w);
    }
    __syncthreads();

    if (t < 256) {
        int node = bin * 256 + t;
        if (node < N_NODES) {
            const float* r = acc2 + t * 33;   // lane i row: banks (i+k)%32 -> conflict-free
            float inv = 1.f / r[32];
            float acc = 0.f;
#pragma unroll
            for (int k = 0; k < 32; ++k) {
                float v = r[k] * inv + b2s[k];
                v = v > 0.f ? v : 0.f;
                acc += v * wos[k];
            }
            out[node] = 1.f / (1.f + __expf(-(acc + bout[0])));
        }
    }
}

extern "C" void kernel_launch(void* const* d_in, const int* in_sizes, int n_in,
                              void* d_out, int out_size, void* d_ws, size_t ws_size,
                              hipStream_t stream) {
    const float* x    = (const float*)d_in[0];
    const int*   ei   = (const int*)  d_in[1];
    const float* W1   = (const float*)d_in[2];
    const float* asw1 = (const float*)d_in[3];
    const float* adw1 = (const float*)d_in[4];
    const float* b1   = (const float*)d_in[5];
    const float* W2   = (const float*)d_in[6];
    const float* asw2 = (const float*)d_in[7];
    const float* adw2 = (const float*)d_in[8];
    const float* b2   = (const float*)d_in[9];
    const float* Wout = (const float*)d_in[10];
    const float* bout = (const float*)d_in[11];
    float* out = (float*)d_out;

    char* p = (char*)d_ws;
    auto carve = [&](size_t bytes) {
        void* r = (void*)p;
        p += (bytes + 255) & ~size_t(255);
        return r;
    };
    float*    xs1      = (float*)   carve((size_t)N_NODES * 8 * 4);   // packed {as1,x}
    __half*   h2h      = (__half*)  carve((size_t)N_NODES * 32 * 2);
    float*    ad1      = (float*)   carve((size_t)N_NODES * 2 * 4);
    float*    as2      = (float*)   carve((size_t)N_NODES * 4);
    float*    ad2      = (float*)   carve((size_t)N_NODES * 4);
    int*      bh       = (int*)     carve((size_t)B_COARSE * NBIN * 4);
    int*      bintot   = (int*)     carve((size_t)NBIN * 4);
    int*      binoff   = (int*)     carve((size_t)(NBIN + 1) * 4);
    unsigned* ebin     = (unsigned*)carve((size_t)ETOT * 4);

    const int TB = 256;

    // ---- CSR-lite build: coarse bucket only (no fine sort) ----
    k_pre     <<<G_NODE1 + B_COARSE, TB, 0, stream>>>(x, W1, asw1, adw1, xs1, ad1, ei, bh);
    k_cscan_a <<<NBIN, TB, 0, stream>>>(bh, bintot);
    k_cscan_b <<<1, TB, 0, stream>>>(bintot, binoff);
    k_cscatter<<<B_COARSE, TB, 0, stream>>>(ei, bh, binoff, ebin);

    // ---- layer 1 aggregate + layer 2 transform (bin-local) ----
    k_gat1bin<<<NBIN, 512, 0, stream>>>(ebin, binoff, xs1, ad1, W1, b1,
                                        W2, asw2, adw2, h2h, as2, ad2);

    // ---- layer 2 aggregate + output head (bin-local) ----
    k_gat2bin<<<NBIN, 512, 0, stream>>>(ebin, binoff, as2, ad2,
                                        (const __half2*)h2h, b2, Wout, bout, out);
}

// Round 17
// 95.975 us; speedup vs baseline: 3.4492x; 3.4492x over previous
//
#include <hip/hip_runtime.h>
#include <hip/hip_fp16.h>

#define N_NODES 50000
#define N_EDGES 800000
#define ETOT    (N_EDGES + N_NODES)   // edges + self loops
#define NEG_SLOPE 0.2f
#define NBIN    ((N_NODES + 255) / 256)     // 196 coarse bins (dst>>8)
#define CHUNK   4096
#define B_COARSE ((ETOT + CHUNK - 1) / CHUNK)  // 208 blocks
#define G_NODE1 ((N_NODES + 3) / 4)            // 12500 blocks for node1 part
#define NG1     (N_NODES / 16)                 // 3125 blocks, 16 nodes each (gat12)

__device__ __forceinline__ float leaky(float v) {
    return v > 0.f ? v : NEG_SLOPE * v;
}

__device__ __forceinline__ void edge_src_dst(const int* ei, int e, int& src, int& dst) {
    if (e < N_EDGES) { src = ei[e]; dst = ei[N_EDGES + e]; }
    else             { src = dst = e - N_EDGES; }
}

// ======== Fused: layer-1 logits + packed {as1,x} record + coarse histogram ========
// xs1[node] = {as1_h0, as1_h1, x0..x5}: 32B aligned -> ONE 64B line per edge gather
__global__ void k_pre(const float* __restrict__ x, const float* __restrict__ W1,
                      const float* __restrict__ a_src1, const float* __restrict__ a_dst1,
                      float* __restrict__ xs1, float* __restrict__ ad1,
                      const int* __restrict__ ei, int* __restrict__ bh) {
    __shared__ int h[NBIN];
    if (blockIdx.x < G_NODE1) {
        int node = blockIdx.x * 4 + (threadIdx.x >> 6);
        if (node >= N_NODES) return;
        int j = threadIdx.x & 63;
        int head = j >> 5;
        float xk[6];
#pragma unroll
        for (int k = 0; k < 6; ++k)
            xk[k] = x[node * 6 + k];
        float hv = 0.f;
#pragma unroll
        for (int k = 0; k < 6; ++k)
            hv += xk[k] * W1[k * 64 + j];
        float s = hv * a_src1[j];
        float d = hv * a_dst1[j];
#pragma unroll
        for (int m = 1; m < 32; m <<= 1) {
            s += __shfl_xor(s, m);
            d += __shfl_xor(d, m);
        }
        if ((j & 31) == 0) {
            xs1[node * 8 + head] = s;          // slots 0,1: alpha_src per head
            ad1[node * 2 + head] = d;
        }
        if (j >= 2 && j < 8)
            xs1[node * 8 + j] = xk[j - 2];     // slots 2..7: x row (already in regs)
    } else {
        int b = blockIdx.x - G_NODE1;
        for (int i = threadIdx.x; i < NBIN; i += 256) h[i] = 0;
        __syncthreads();
        int base = b * CHUNK;
        int lim = min(base + CHUNK, ETOT);
        for (int e = base + threadIdx.x; e < lim; e += 256) {
            int s, d; edge_src_dst(ei, e, s, d);
            atomicAdd(&h[d >> 8], 1);
        }
        __syncthreads();
        for (int i = threadIdx.x; i < NBIN; i += 256)
            bh[b * NBIN + i] = h[i];
    }
}

// Parallel segmented scan: one block per bin scans its 208 per-chunk counts
__global__ void k_cscan_a(int* __restrict__ bh, int* __restrict__ bintot) {
    __shared__ int s[256];
    int bin = blockIdx.x;
    int t = threadIdx.x;
    int v = (t < B_COARSE) ? bh[t * NBIN + bin] : 0;
    int x = v;
    s[t] = x;
    __syncthreads();
#pragma unroll
    for (int o = 1; o < 256; o <<= 1) {
        int tt = (t >= o) ? s[t - o] : 0;
        __syncthreads();
        x += tt;
        s[t] = x;
        __syncthreads();
    }
    if (t < B_COARSE) bh[t * NBIN + bin] = x - v;   // exclusive within-bin start per chunk
    if (t == 255) bintot[bin] = x;
}

// Tiny cross-bin exclusive scan of the 196 totals
__global__ void k_cscan_b(const int* __restrict__ bintot, int* __restrict__ binoff) {
    __shared__ int s[256];
    int t = threadIdx.x;
    int v = (t < NBIN) ? bintot[t] : 0;
    int x = v;
    s[t] = x;
    __syncthreads();
#pragma unroll
    for (int o = 1; o < 256; o <<= 1) {
        int tt = (t >= o) ? s[t - o] : 0;
        __syncthreads();
        x += tt;
        s[t] = x;
        __syncthreads();
    }
    if (t < NBIN) binoff[t] = x - v;
    if (t == 255) binoff[NBIN] = x;          // == ETOT
}

__global__ void k_cscatter(const int* __restrict__ ei, const int* __restrict__ bh,
                           const int* __restrict__ binoff, unsigned* __restrict__ ebin) {
    __shared__ int cur[NBIN];
    for (int i = threadIdx.x; i < NBIN; i += 256)
        cur[i] = bh[blockIdx.x * NBIN + i] + binoff[i];
    __syncthreads();
    int base = blockIdx.x * CHUNK;
    int lim = min(base + CHUNK, ETOT);
    for (int e = base + threadIdx.x; e < lim; e += 256) {
        int s, d; edge_src_dst(ei, e, s, d);
        int pos = atomicAdd(&cur[d >> 8], 1);
        ebin[pos] = ((unsigned)s << 8) | (unsigned)(d & 255);
    }
}

__global__ void k_fine(const unsigned* __restrict__ ebin, const int* __restrict__ binoff,
                       int* __restrict__ rowstart, int* __restrict__ csr_src) {
    __shared__ int h[256];
    __shared__ int cur[256];
    int bin = blockIdx.x;
    int beg = binoff[bin], end = binoff[bin + 1];
    int t = threadIdx.x;
    h[t] = 0;
    __syncthreads();
    for (int i = beg + t; i < end; i += 256)
        atomicAdd(&h[ebin[i] & 255u], 1);
    __syncthreads();
    int v = h[t];
    int x = v;
    cur[t] = x;
    __syncthreads();
#pragma unroll
    for (int o = 1; o < 256; o <<= 1) {
        int tt = (t >= o) ? cur[t - o] : 0;
        __syncthreads();
        x += tt;
        cur[t] = x;
        __syncthreads();
    }
    int start = beg + x - v;
    int node = bin * 256 + t;
    if (node < N_NODES) rowstart[node] = start;
    if (bin == NBIN - 1 && t == 0) rowstart[N_NODES] = ETOT;
    cur[t] = start;
    __syncthreads();
    for (int i = beg + t; i < end; i += 256) {
        unsigned p = ebin[i];
        int pos = atomicAdd(&cur[p & 255u], 1);
        csr_src[pos] = (int)(p >> 8);
    }
}

// ============ Fused layer-1 aggregate (o1 in LDS) + layer-2 transform ============
// Block = 16 nodes. Phase 1: gat1 via packed one-line gathers -> LDS o1 tile.
// Phase 2: h2 = o1 @ W2 from LDS, fp16-pack h2, layer-2 logits.
__global__ void k_gat12(const int* __restrict__ csr_src, const int* __restrict__ rowstart,
                        const float* __restrict__ xs1, const float* __restrict__ ad1,
                        const float* __restrict__ W1, const float* __restrict__ b1,
                        const float* __restrict__ W2, const float* __restrict__ as_w2,
                        const float* __restrict__ ad_w2, __half* __restrict__ h2h,
                        float* __restrict__ as2, float* __restrict__ ad2) {
    __shared__ float W2s[64 * 32];
    __shared__ float o1s[16 * 66];   // stride 66: bank-safe
    int t = threadIdx.x;
    for (int i = t; i < 64 * 32; i += 256)
        W2s[i] = W2[i];

    int l = t & 15;          // lane within 16-group == feature index (phase 2)
    int ln = t >> 4;         // local node 0..15
    int node = blockIdx.x * 16 + ln;     // N_NODES == 3125*16 exactly

    float p[4][6];
    float bv[4];
#pragma unroll
    for (int m = 0; m < 4; ++m) {
        int c = l + 16 * m;
#pragma unroll
        for (int k = 0; k < 6; ++k)
            p[m][k] = W1[k * 64 + c];
        bv[m] = b1[c];
    }

    // ---- phase 1: gat1 (one 64B line per edge) ----
    int beg = rowstart[node], end = rowstart[node + 1];
    float2 adv = ((const float2*)ad1)[node];

    float a0 = 0, a1 = 0, a2 = 0, a3 = 0, a4 = 0, a5 = 0;
    float c0 = 0, c1 = 0, c2 = 0, c3 = 0, c4 = 0, c5 = 0;
    float dp0 = 0, dp1 = 0;
    for (int i = beg + l; i < end; i += 16) {
        int s = csr_src[i];
        const float4* xp = (const float4*)(xs1 + (size_t)s * 8);
        float4 A = xp[0], B = xp[1];   // A = {as0, as1, x0, x1}, B = {x2..x5}
        float w0 = __expf(leaky(A.x + adv.x));   // logits O(1): no max needed
        float w1 = __expf(leaky(A.y + adv.y));
        dp0 += w0;
        dp1 += w1;
        a0 += w0 * A.z; a1 += w0 * A.w; a2 += w0 * B.x;
        a3 += w0 * B.y; a4 += w0 * B.z; a5 += w0 * B.w;
        c0 += w1 * A.z; c1 += w1 * A.w; c2 += w1 * B.x;
        c3 += w1 * B.y; c4 += w1 * B.z; c5 += w1 * B.w;
    }
#pragma unroll
    for (int o = 8; o; o >>= 1) {
        a0 += __shfl_xor(a0, o); a1 += __shfl_xor(a1, o); a2 += __shfl_xor(a2, o);
        a3 += __shfl_xor(a3, o); a4 += __shfl_xor(a4, o); a5 += __shfl_xor(a5, o);
        c0 += __shfl_xor(c0, o); c1 += __shfl_xor(c1, o); c2 += __shfl_xor(c2, o);
        c3 += __shfl_xor(c3, o); c4 += __shfl_xor(c4, o); c5 += __shfl_xor(c5, o);
        dp0 += __shfl_xor(dp0, o); dp1 += __shfl_xor(dp1, o);
    }
    float inv0 = 1.f / dp0;
    float inv1 = 1.f / dp1;
#pragma unroll
    for (int m = 0; m < 4; ++m) {
        float dot;
        if (m < 2)
            dot = a0 * p[m][0] + a1 * p[m][1] + a2 * p[m][2]
                + a3 * p[m][3] + a4 * p[m][4] + a5 * p[m][5];
        else
            dot = c0 * p[m][0] + c1 * p[m][1] + c2 * p[m][2]
                + c3 * p[m][3] + c4 * p[m][4] + c5 * p[m][5];
        float v = dot * (m < 2 ? inv0 : inv1) + bv[m];
        o1s[ln * 66 + l + 16 * m] = v > 0.f ? v : 0.f;   // bias+relu, LDS only
    }
    __syncthreads();

    // ---- phase 2: node2 (thread -> node ln, features l and l+16) ----
    float h0 = 0.f, h1 = 0.f;
#pragma unroll
    for (int k = 0; k < 64; ++k) {
        float ov = o1s[ln * 66 + k];
        h0 += ov * W2s[k * 32 + l];
        h1 += ov * W2s[k * 32 + l + 16];
    }
    h2h[node * 32 + l] = __float2half(h0);
    h2h[node * 32 + l + 16] = __float2half(h1);
    float s2 = h0 * as_w2[l] + h1 * as_w2[l + 16];
    float d2 = h0 * ad_w2[l] + h1 * ad_w2[l + 16];
#pragma unroll
    for (int o = 8; o; o >>= 1) {
        s2 += __shfl_xor(s2, o);
        d2 += __shfl_xor(d2, o);
    }
    if (l == 0) {
        as2[node] = s2;
        ad2[node] = d2;
    }
}

// ============ Layer 2 fused softmax(no-max) + aggregate + output head ============
// one wave per node: 4 edge slots x 16 feature-pair lanes (fp16x2 gather)
__global__ void k_gat2(const int* __restrict__ csr_src, const int* __restrict__ rowstart,
                       const float* __restrict__ as2, const float* __restrict__ ad2,
                       const __half2* __restrict__ h2h, const float* __restrict__ b2,
                       const float* __restrict__ Wout, const float* __restrict__ bout,
                       float* __restrict__ out) {
    int node = blockIdx.x * 4 + (threadIdx.x >> 6);
    if (node >= N_NODES) return;
    int j = threadIdx.x & 63;
    int f = j & 15;          // feature pair (2f, 2f+1)
    int slot = j >> 4;       // edge slot 0..3
    int beg = rowstart[node], end = rowstart[node + 1];
    float adv = ad2[node];

    float accx = 0.f, accy = 0.f, dp = 0.f;
    for (int base = beg; base < end; base += 64) {
        int idx = base + j;
        float w = 0.f;
        int s = 0;
        if (idx < end) {
            s = csr_src[idx];
            w = __expf(leaky(as2[s] + adv));
            dp += w;
        }
        int cnt = min(64, end - base);
        for (int k = 0; k < cnt; k += 4) {
            int   sk = __shfl(s, k + slot);     // w=0 for OOB lanes -> no tail case
            float wk = __shfl(w, k + slot);
            float2 hv = __half22float2(h2h[sk * 16 + f]);
            accx += wk * hv.x;
            accy += wk * hv.y;
        }
    }
#pragma unroll
    for (int o = 32; o; o >>= 1)
        dp += __shfl_xor(dp, o);
    accx += __shfl_xor(accx, 16); accy += __shfl_xor(accy, 16);
    accx += __shfl_xor(accx, 32); accy += __shfl_xor(accy, 32);

    float inv = 1.f / dp;
    float vx = accx * inv + b2[2 * f];
    float vy = accy * inv + b2[2 * f + 1];
    vx = vx > 0.f ? vx : 0.f;
    vy = vy > 0.f ? vy : 0.f;
    float t = vx * Wout[2 * f] + vy * Wout[2 * f + 1];
#pragma unroll
    for (int o = 8; o; o >>= 1)
        t += __shfl_xor(t, o);
    if (j == 0)
        out[node] = 1.f / (1.f + __expf(-(t + bout[0])));
}

extern "C" void kernel_launch(void* const* d_in, const int* in_sizes, int n_in,
                              void* d_out, int out_size, void* d_ws, size_t ws_size,
                              hipStream_t stream) {
    const float* x    = (const float*)d_in[0];
    const int*   ei   = (const int*)  d_in[1];
    const float* W1   = (const float*)d_in[2];
    const float* asw1 = (const float*)d_in[3];
    const float* adw1 = (const float*)d_in[4];
    const float* b1   = (const float*)d_in[5];
    const float* W2   = (const float*)d_in[6];
    const float* asw2 = (const float*)d_in[7];
    const float* adw2 = (const float*)d_in[8];
    const float* b2   = (const float*)d_in[9];
    const float* Wout = (const float*)d_in[10];
    const float* bout = (const float*)d_in[11];
    float* out = (float*)d_out;

    char* p = (char*)d_ws;
    auto carve = [&](size_t bytes) {
        void* r = (void*)p;
        p += (bytes + 255) & ~size_t(255);
        return r;
    };
    float*    xs1      = (float*)   carve((size_t)N_NODES * 8 * 4);   // packed {as1,x}
    __half*   h2h      = (__half*)  carve((size_t)N_NODES * 32 * 2);
    float*    ad1      = (float*)   carve((size_t)N_NODES * 2 * 4);
    float*    as2      = (float*)   carve((size_t)N_NODES * 4);
    float*    ad2      = (float*)   carve((size_t)N_NODES * 4);
    int*      bh       = (int*)     carve((size_t)B_COARSE * NBIN * 4);
    int*      bintot   = (int*)     carve((size_t)NBIN * 4);
    int*      binoff   = (int*)     carve((size_t)(NBIN + 1) * 4);
    unsigned* ebin     = (unsigned*)carve((size_t)ETOT * 4);
    int*      rowstart = (int*)     carve((size_t)(N_NODES + 1) * 4);
    int*      csr_src  = (int*)     carve((size_t)ETOT * 4);

    const int TB = 256;

    // ---- CSR build (+ fused layer-1 logits / packed record) ----
    k_pre     <<<G_NODE1 + B_COARSE, TB, 0, stream>>>(x, W1, asw1, adw1, xs1, ad1, ei, bh);
    k_cscan_a <<<NBIN, TB, 0, stream>>>(bh, bintot);
    k_cscan_b <<<1, TB, 0, stream>>>(bintot, binoff);
    k_cscatter<<<B_COARSE, TB, 0, stream>>>(ei, bh, binoff, ebin);
    k_fine    <<<NBIN, TB, 0, stream>>>(ebin, binoff, rowstart, csr_src);

    // ---- fused layer-1 aggregate + layer-2 transform ----
    k_gat12<<<NG1, TB, 0, stream>>>(csr_src, rowstart, xs1, ad1, W1, b1,
                                    W2, asw2, adw2, h2h, as2, ad2);

    // ---- layer 2 aggregate + output head ----
    k_gat2 <<<(N_NODES + 3) / 4, TB, 0, stream>>>(csr_src, rowstart, as2, ad2,
                                                  (const __half2*)h2h, b2, Wout, bout, out);
}